// Round 10
// baseline (996.267 us; speedup 1.0000x reference)
//
#include <hip/hip_runtime.h>
#include <math.h>

#define Nn 1024
#define Ee 4
#define Uu 32
#define BLOCK_ROWS 32  // 4 waves x 8 rows

// ---------------------------------------------------------------------------
// pre-kernel: grid (128, 5), block 256. blockIdx.y = e (0..3 edge types,
// 4 = residual W2/b2).
//   e<4 : hpre_t[b][e][u][n] = sum_f ann[b,n,f]*Wa[e,f,u] + ba[e,u]  (u-major!)
//   e==4: res[b][n][u]       = sum_f ann[b,n,f]*W2[f,u]  + b2[u]
// ---------------------------------------------------------------------------
template <int F, int FA>
__global__ __launch_bounds__(256) void pre_kernel(
    const float* __restrict__ annA, const float* __restrict__ annB,
    const float* __restrict__ Wa, const float* __restrict__ ba,
    const float* __restrict__ W2, const float* __restrict__ b2,
    float* __restrict__ hpre_t, float* __restrict__ res)
{
    const int e = blockIdx.y;            // 0..4
    __shared__ float wlds[F * Uu];
    __shared__ float blds[Uu];
    const int tid = threadIdx.x;
    const float* wsrc = (e < 4) ? (Wa + (size_t)e * F * Uu) : W2;
    const float* bsrc = (e < 4) ? (ba + (size_t)e * Uu) : b2;
    for (int i = tid; i < F * Uu; i += 256) wlds[i] = wsrc[i];
    if (tid < Uu) blds[tid] = bsrc[tid];
    __syncthreads();

    const int g = blockIdx.x * 256 + tid;   // flat row in [0, B*N)
    const int b = g >> 10;
    const int n = g & 1023;

    float4 a4[F / 4];
    {
        const float4* rA = (const float4*)(annA + (size_t)g * FA);
#pragma unroll
        for (int i = 0; i < FA / 4; ++i) a4[i] = rA[i];
        if constexpr (F > FA) {
            const float4* rB = (const float4*)(annB + (size_t)g * (F - FA));
#pragma unroll
            for (int i = 0; i < (F - FA) / 4; ++i) a4[FA / 4 + i] = rB[i];
        }
    }

    float4 acc[8];
    const float4* bb = (const float4*)blds;
#pragma unroll
    for (int uq = 0; uq < 8; ++uq) acc[uq] = bb[uq];
    const float4* w4 = (const float4*)wlds;
#pragma unroll
    for (int f4 = 0; f4 < F / 4; ++f4) {
        const float4 av = a4[f4];
#pragma unroll
        for (int c = 0; c < 4; ++c) {
            const float s = (c == 0) ? av.x : (c == 1) ? av.y : (c == 2) ? av.z : av.w;
#pragma unroll
            for (int uq = 0; uq < 8; ++uq) {
                const float4 w = w4[(f4 * 4 + c) * 8 + uq];  // uniform -> broadcast
                acc[uq].x = fmaf(s, w.x, acc[uq].x);
                acc[uq].y = fmaf(s, w.y, acc[uq].y);
                acc[uq].z = fmaf(s, w.z, acc[uq].z);
                acc[uq].w = fmaf(s, w.w, acc[uq].w);
            }
        }
    }
    if (e < 4) {
        float* dst = hpre_t + ((size_t)(b * 4 + e) * Uu) * Nn + n;  // [b][e][u][n]
#pragma unroll
        for (int uq = 0; uq < 8; ++uq) {
            dst[(uq * 4 + 0) * Nn] = acc[uq].x;
            dst[(uq * 4 + 1) * Nn] = acc[uq].y;
            dst[(uq * 4 + 2) * Nn] = acc[uq].z;
            dst[(uq * 4 + 3) * Nn] = acc[uq].w;
        }
    } else {
        float4* dst = (float4*)(res + (size_t)g * Uu);
#pragma unroll
        for (int uq = 0; uq < 8; ++uq) dst[uq] = acc[uq];
    }
}

// ---------------------------------------------------------------------------
// main kernel: out[b][n][u] = tanh( sum_e sum_m adj[b,e,n,m]*h_pre[b,e,m,u]
//                                   + res[b,n,u] )
// ZERO-DUPLICATION layout (the R2..R9 plateau was L1-return/TD bandwidth
// burned on duplicated lane loads):
//   lane = (rg: 0..3) x (ms m-quad: 0..15); wave owns 8 rows; lane owns rows
//   {wrow+rg, wrow+rg+4} at its m-quad -> every adj load instruction covers
//   64 UNIQUE (row, quad) slots. acc = accA[32 u] / accB[32 u] per lane.
//   h staged in LDS once per block: 16 stages of [32 u][256 m] (32 KB),
//   REGISTER-staged (global->reg->ds_write; no global_load_lds, so ds_reads
//   depend only on lgkmcnt -- no conservative vmcnt(0) drains).
// Stage body: [lgkm+barrier B] [ds_write h(s) (vmem wait is counted; h(s)
// landed a stage ago)] [issue h(s+1)->regs (WAR keeps it after the write)]
// [prefetch chunk-0 adj] [lgkm+barrier D] [4 barrier-free chunks: adj
// global->reg (compiler hoists c+1 over c's FMAs), ds_read_b128 (2-way bank
// = free), 256 FMA/lane/chunk].
// Epilogue: shfl_xor over ms lanes -> ms==0 lanes add residual, tanh, store.
// ---------------------------------------------------------------------------
__global__ __launch_bounds__(256) void gcn_main_kernel(
    const float* __restrict__ adj,     // [B,E,N,N]
    const float* __restrict__ hpre_t,  // [B,E,U,N]
    const float* __restrict__ res,     // [B,N,U]
    float* __restrict__ out)           // [B,N,U]
{
    __shared__ float buf[Uu * 256];    // 32 KB, [u][256 m] of current stage

    const int bid = blockIdx.x;                       // 1024 blocks
    const int swz = (bid & 7) * 128 + (bid >> 3);     // XCD-aware, bijective
    const int b = swz >> 5;                           // 32 blocks per b
    const int n0 = (swz & 31) * BLOCK_ROWS;
    const int tid = threadIdx.x;
    const int w = tid >> 6;       // wave 0..3
    const int lane = tid & 63;
    const int ms = lane & 15;     // m-quad 0..15
    const int rg = lane >> 4;     // row-group 0..3
    const int wrow = n0 + w * 8;  // 8 rows per wave

    const float* adjb = adj + (size_t)b * Ee * Nn * Nn;
    const float* hpb  = hpre_t + (size_t)b * Ee * Uu * Nn;

    // h staging assignment: thread -> (u-row uh, base quad qb); instr k loads
    // quad qb+8k. Per instr: 32 u x 8 quads, coalesced 128 B per u-group.
    const int uh = tid >> 3, qb = tid & 7;
    float4* buf4 = (float4*)buf;

    float accA[32], accB[32];
#pragma unroll
    for (int u = 0; u < 32; ++u) { accA[u] = 0.f; accB[u] = 0.f; }

    float4 hr[8];

    // prologue: issue h(stage 0) -> regs
    {
        const float* hs = hpb + (size_t)uh * Nn + qb * 4;   // e=0, mq=0
#pragma unroll
        for (int k = 0; k < 8; ++k) hr[k] = *(const float4*)(hs + k * 32);
    }

    for (int s = 0; s < 16; ++s) {
        const int e = s >> 2, mq = s & 3;

        // B: all waves done reading buf (previous stage)
        asm volatile("s_waitcnt lgkmcnt(0)" ::: "memory");
        __builtin_amdgcn_s_barrier();

        // C: ds_write h(s) (auto vmem wait is counted; h(s) landed long ago)
#pragma unroll
        for (int k = 0; k < 8; ++k) buf4[uh * 64 + qb + 8 * k] = hr[k];

        // A: issue h(s+1) -> hr (WAR on hr keeps this after the ds_write)
        {
            const int s2 = (s < 15) ? s + 1 : 15;
            const int e2 = s2 >> 2, mq2 = s2 & 3;
            const float* hs = hpb + ((size_t)e2 * Uu + uh) * Nn + mq2 * 256 + qb * 4;
#pragma unroll
            for (int k = 0; k < 8; ++k) hr[k] = *(const float4*)(hs + k * 32);
        }

        // chunk-0 adj prefetch (global->reg; rides over the barrier rendezvous)
        const float* ap0 = adjb + ((size_t)e * Nn + wrow + rg) * Nn + mq * 256 + ms * 4;
        float4 a00 = *(const float4*)(ap0);
        float4 a01 = *(const float4*)(ap0 + 4 * Nn);
        __builtin_amdgcn_sched_barrier(0);

        // D: buf visible to all
        asm volatile("s_waitcnt lgkmcnt(0)" ::: "memory");
        __builtin_amdgcn_s_barrier();
        __builtin_amdgcn_sched_barrier(0);

        // 4 barrier-free chunks of 64 m
#pragma unroll
        for (int c = 0; c < 4; ++c) {
            float4 av0, av1;
            if (c == 0) { av0 = a00; av1 = a01; }
            else {
                const float* ap = ap0 + c * 64;
                av0 = *(const float4*)(ap);
                av1 = *(const float4*)(ap + 4 * Nn);
            }
#pragma unroll
            for (int u = 0; u < 32; ++u) {
                const float4 hv = buf4[u * 64 + c * 16 + ms];
                accA[u] = fmaf(av0.x, hv.x, fmaf(av0.y, hv.y,
                           fmaf(av0.z, hv.z, fmaf(av0.w, hv.w, accA[u]))));
                accB[u] = fmaf(av1.x, hv.x, fmaf(av1.y, hv.y,
                           fmaf(av1.z, hv.z, fmaf(av1.w, hv.w, accB[u]))));
            }
        }
    }

    // reduce partial sums across the 16 ms lanes (lane bits 0..3)
#pragma unroll
    for (int u = 0; u < 32; ++u) {
        float v = accA[u];
        v += __shfl_xor(v, 1);
        v += __shfl_xor(v, 2);
        v += __shfl_xor(v, 4);
        v += __shfl_xor(v, 8);
        accA[u] = v;
        float v2 = accB[u];
        v2 += __shfl_xor(v2, 1);
        v2 += __shfl_xor(v2, 2);
        v2 += __shfl_xor(v2, 4);
        v2 += __shfl_xor(v2, 8);
        accB[u] = v2;
    }

    // epilogue: ms==0 lanes hold full sums for rows wrow+rg / wrow+rg+4
    if (ms == 0) {
        const int r0 = wrow + rg, r1 = wrow + rg + 4;
        const float4* rp0 = (const float4*)(res + ((size_t)b * Nn + r0) * Uu);
        const float4* rp1 = (const float4*)(res + ((size_t)b * Nn + r1) * Uu);
        float4* op0 = (float4*)(out + ((size_t)b * Nn + r0) * Uu);
        float4* op1 = (float4*)(out + ((size_t)b * Nn + r1) * Uu);
#pragma unroll
        for (int q = 0; q < 8; ++q) {
            const float4 rv0 = rp0[q];
            const float4 rv1 = rp1[q];
            float4 o0, o1;
            o0.x = tanhf(accA[q * 4 + 0] + rv0.x);
            o0.y = tanhf(accA[q * 4 + 1] + rv0.y);
            o0.z = tanhf(accA[q * 4 + 2] + rv0.z);
            o0.w = tanhf(accA[q * 4 + 3] + rv0.w);
            o1.x = tanhf(accB[q * 4 + 0] + rv1.x);
            o1.y = tanhf(accB[q * 4 + 1] + rv1.y);
            o1.z = tanhf(accB[q * 4 + 2] + rv1.z);
            o1.w = tanhf(accB[q * 4 + 3] + rv1.w);
            op0[q] = o0;
            op1[q] = o1;
        }
    }
}

extern "C" void kernel_launch(void* const* d_in, const int* in_sizes, int n_in,
                              void* d_out, int out_size, void* d_ws, size_t ws_size,
                              hipStream_t stream)
{
    const float* n_tensor = (const float*)d_in[0];  // [32,1024,32]
    const float* adj      = (const float*)d_in[1];  // [32,4,1024,1024]
    const float* W_adj0   = (const float*)d_in[2];  // [4,32,32]
    const float* b_adj0   = (const float*)d_in[3];  // [4,32]
    const float* W2_0     = (const float*)d_in[4];  // [32,32]
    const float* b2_0     = (const float*)d_in[5];  // [32]
    const float* W_adj1   = (const float*)d_in[6];  // [4,64,32]
    const float* b_adj1   = (const float*)d_in[7];  // [4,32]
    const float* W2_1     = (const float*)d_in[8];  // [64,32]
    const float* b2_1     = (const float*)d_in[9];  // [32]
    float* outp = (float*)d_out;

    float* ws   = (float*)d_ws;
    float* hpre = ws;                            // 16 MiB
    float* resb = ws + (size_t)4 * 1024 * 1024;  // 4 MiB
    float* h0   = ws + (size_t)5 * 1024 * 1024;  // 4 MiB

    dim3 pre_grid(128, 5);

    // layer 0 (F = 32)
    pre_kernel<32, 32><<<pre_grid, 256, 0, stream>>>(n_tensor, nullptr, W_adj0, b_adj0,
                                                     W2_0, b2_0, hpre, resb);
    gcn_main_kernel<<<1024, 256, 0, stream>>>(adj, hpre, resb, h0);

    // layer 1 (F = 64, ann = concat(n_tensor, h0))
    pre_kernel<64, 32><<<pre_grid, 256, 0, stream>>>(n_tensor, h0, W_adj1, b_adj1,
                                                     W2_1, b2_1, hpre, resb);
    gcn_main_kernel<<<1024, 256, 0, stream>>>(adj, hpre, resb, outp);
}